// Round 1
// baseline (296.827 us; speedup 1.0000x reference)
//
#include <hip/hip_runtime.h>

typedef unsigned short u16;
typedef __attribute__((ext_vector_type(8))) u16    u16x8;
typedef __attribute__((ext_vector_type(4))) u16    u16x4;
typedef __attribute__((ext_vector_type(8))) __bf16 bf16x8;
typedef __attribute__((ext_vector_type(4))) float  f32x4;

__device__ __forceinline__ u16 f2bf(float f) {
    unsigned u = __float_as_uint(f);
    u += 0x7fffu + ((u >> 16) & 1u);   // RNE
    return (u16)(u >> 16);
}
__device__ __forceinline__ bf16x8 ldbf8(const u16* p) {
    return __builtin_bit_cast(bf16x8, *(const u16x8*)p);
}
__device__ __forceinline__ f32x4 mfma16(bf16x8 a, bf16x8 b, f32x4 c) {
    return __builtin_amdgcn_mfma_f32_16x16x32_bf16(a, b, c, 0, 0, 0);
}

// ---------------- weight transpose + cast:  Wt[n][k] = bf16(W[k][n]) ----------------
__global__ void transpose_cast(const float* __restrict__ W, u16* __restrict__ Wt, int K, int N) {
    __shared__ float tile[32][33];
    int kb = blockIdx.x * 32, nb = blockIdx.y * 32;
    int tx = threadIdx.x, ty = threadIdx.y;          // (32, 8)
#pragma unroll
    for (int i = 0; i < 32; i += 8)
        tile[ty + i][tx] = W[(size_t)(kb + ty + i) * N + nb + tx];
    __syncthreads();
#pragma unroll
    for (int i = 0; i < 32; i += 8)
        Wt[(size_t)(nb + ty + i) * K + kb + tx] = f2bf(tile[tx][ty + i]);
}

// ---------------- LayerNorm + cast: xn = bf16(LN(x)*gamma), xb = bf16(x) ----------------
__global__ __launch_bounds__(256) void ln_cast(const float* __restrict__ x, const float* __restrict__ gamma,
                                               u16* __restrict__ xn, u16* __restrict__ xb) {
    const int row = blockIdx.x;          // 4096 rows of 1024
    const int t = threadIdx.x;           // 256 threads, 4 floats each
    const float4 v = ((const float4*)(x + (size_t)row * 1024))[t];
    float s  = v.x + v.y + v.z + v.w;
    float s2 = v.x * v.x + v.y * v.y + v.z * v.z + v.w * v.w;
#pragma unroll
    for (int off = 32; off; off >>= 1) { s += __shfl_down(s, off); s2 += __shfl_down(s2, off); }
    __shared__ float red[2][4];
    const int w = t >> 6, lane = t & 63;
    if (lane == 0) { red[0][w] = s; red[1][w] = s2; }
    __syncthreads();
    s  = red[0][0] + red[0][1] + red[0][2] + red[0][3];
    s2 = red[1][0] + red[1][1] + red[1][2] + red[1][3];
    const float mu  = s * (1.0f / 1024.0f);
    const float var = s2 * (1.0f / 1024.0f) - mu * mu;
    const float rs  = rsqrtf(var + 1e-5f);
    const float4 g = ((const float4*)gamma)[t];
    u16x4 on, ob;
    on.x = f2bf((v.x - mu) * rs * g.x); on.y = f2bf((v.y - mu) * rs * g.y);
    on.z = f2bf((v.z - mu) * rs * g.z); on.w = f2bf((v.w - mu) * rs * g.w);
    ob.x = f2bf(v.x); ob.y = f2bf(v.y); ob.z = f2bf(v.z); ob.w = f2bf(v.w);
    ((u16x4*)(xn + (size_t)row * 1024))[t] = on;
    ((u16x4*)(xb + (size_t)row * 1024))[t] = ob;
}

// ---------------- GEMM: C[M,N] = A[M,K] @ Bt[N,K]^T (bf16 in, f32 acc) ----------------
// EPI 0: bf16 row-major C.  EPI 1: f32 row-major C.  EPI 2: KV split (k row-major, v transposed).
template<int BM, int BN, int EPI>
__global__ __launch_bounds__(256) void gemm_bt(const u16* __restrict__ A, const u16* __restrict__ Bt,
                                               u16* __restrict__ Cb, float* __restrict__ Cf,
                                               u16* __restrict__ Cv, int M, int N, int K) {
    constexpr int WM = BM / 2, WN = BN / 2, FM = WM / 16, FN = WN / 16;
    constexpr int CHA = BM * 4, CH = (BM + BN) * 4, ITERS = CH / 256;  // 16B chunks, BK=32
    __shared__ __align__(16) u16 lds[2][(BM + BN) * 32];
    const int tid = threadIdx.x;
    const int m0 = blockIdx.x * BM, n0 = blockIdx.y * BN;
    const int w = tid >> 6, lane = tid & 63, cl = lane & 15, kg = lane >> 4;
    const int wr = w >> 1, wc = w & 1;

    auto stage = [&](int buf, int k0) {
#pragma unroll
        for (int it = 0; it < ITERS; ++it) {
            int c = it * 256 + tid;
            const u16* g;
            if (c < CHA) { int r = c >> 2, cc = c & 3; g = A  + (size_t)(m0 + r) * K + k0 + cc * 8; }
            else { int c2 = c - CHA; int r = c2 >> 2, cc = c2 & 3; g = Bt + (size_t)(n0 + r) * K + k0 + cc * 8; }
            __builtin_amdgcn_global_load_lds(
                (const __attribute__((address_space(1))) unsigned int*)g,
                (__attribute__((address_space(3))) unsigned int*)&lds[buf][c * 8], 16, 0, 0);
        }
    };

    const f32x4 zero = {0.f, 0.f, 0.f, 0.f};
    f32x4 acc[FM][FN];
#pragma unroll
    for (int m = 0; m < FM; m++)
#pragma unroll
        for (int n = 0; n < FN; n++) acc[m][n] = zero;

    const int KT = K / 32;
    stage(0, 0);
    for (int t = 0; t < KT; ++t) {
        __syncthreads();                       // drains vmcnt: buf[t&1] staged, prev reads done
        if (t + 1 < KT) stage((t + 1) & 1, (t + 1) * 32);
        const u16* As = &lds[t & 1][0];
        const u16* Bs = &lds[t & 1][BM * 32];
        bf16x8 af[FM], bfr[FN];
#pragma unroll
        for (int m = 0; m < FM; m++) af[m]  = ldbf8(As + (wr * WM + m * 16 + cl) * 32 + kg * 8);
#pragma unroll
        for (int n = 0; n < FN; n++) bfr[n] = ldbf8(Bs + (wc * WN + n * 16 + cl) * 32 + kg * 8);
#pragma unroll
        for (int m = 0; m < FM; m++)
#pragma unroll
            for (int n = 0; n < FN; n++) acc[m][n] = mfma16(af[m], bfr[n], acc[m][n]);
    }

#pragma unroll
    for (int m = 0; m < FM; m++)
#pragma unroll
        for (int n = 0; n < FN; n++)
#pragma unroll
            for (int r = 0; r < 4; r++) {
                const int row = m0 + wr * WM + m * 16 + kg * 4 + r;   // D: row=(lane>>4)*4+reg
                const int col = n0 + wc * WN + n * 16 + cl;           //    col=lane&15
                const float v = acc[m][n][r];
                if constexpr (EPI == 0) Cb[(size_t)row * N + col] = f2bf(v);
                else if constexpr (EPI == 1) Cf[(size_t)row * N + col] = v;
                else {
                    if (col < 64) Cb[(size_t)row * 64 + col] = f2bf(v);
                    else { int bb = row >> 11, s = row & 2047;
                           Cv[((size_t)bb * 64 + (col - 64)) * 2048 + s] = f2bf(v); }
                }
            }
}

// ---------------- causal flash attention, MQA (1 KV head), Dh=64 ----------------
// q: [B,S,1024] bf16 (head-major cols), k: [B,S,64], vt: [B,64,S], o: [B,S,1024]
__global__ __launch_bounds__(256) void attn_fwd(const u16* __restrict__ q, const u16* __restrict__ k,
                                                const u16* __restrict__ vt, u16* __restrict__ o) {
    constexpr int S = 2048;
    const int bid = blockIdx.x;                       // b*512 + h*32 + qt
    const int qt = bid & 31, h = (bid >> 5) & 15, b = bid >> 9;
    const int tid = threadIdx.x, w = tid >> 6, lane = tid & 63, cl = lane & 15, kg = lane >> 4;
    const int q0 = qt * 64, qbase = q0 + w * 16;      // this wave's 16 q-rows
    __shared__ __align__(16) u16 p_lds[4][16][72];    // pad 72 -> 144B rows (16B-aligned, 2-way banks)

    // Q fragment (A-layout: row=lane&15, k=(lane>>4)*8+j), hoisted
    const u16* qp = q + ((size_t)(b * S + qbase + cl)) * 1024 + h * 64;
    const bf16x8 qf0 = ldbf8(qp + kg * 8);
    const bf16x8 qf1 = ldbf8(qp + 32 + kg * 8);

    const f32x4 zero = {0.f, 0.f, 0.f, 0.f};
    f32x4 accO[4]; 
#pragma unroll
    for (int d = 0; d < 4; d++) accO[d] = zero;
    float m_run[4] = {-1e30f, -1e30f, -1e30f, -1e30f};
    float l_run[4] = {0.f, 0.f, 0.f, 0.f};

    const int imax = qbase + 15;
    for (int j0 = 0; j0 <= imax; j0 += 64) {
        // ---- S = scale * Q K^T  (4 j-subtiles of 16) ----
        f32x4 sf[4];
#pragma unroll
        for (int jn = 0; jn < 4; jn++) {
            const u16* kp = k + ((size_t)(b * S + j0 + jn * 16 + cl)) * 64 + kg * 8;
            f32x4 c = zero;
            c = mfma16(qf0, ldbf8(kp), c);
            c = mfma16(qf1, ldbf8(kp + 32), c);
            sf[jn] = c;
        }
        // ---- mask + row max ----
        float mrow[4] = {-1e30f, -1e30f, -1e30f, -1e30f};
#pragma unroll
        for (int jn = 0; jn < 4; jn++)
#pragma unroll
            for (int r = 0; r < 4; r++) {
                float s = sf[jn][r] * 0.125f;
                const int j = j0 + jn * 16 + cl;
                const int i = qbase + kg * 4 + r;
                if (j > i) s = -1e30f;
                sf[jn][r] = s;
                mrow[r] = fmaxf(mrow[r], s);
            }
#pragma unroll
        for (int off = 1; off < 16; off <<= 1)
#pragma unroll
            for (int r = 0; r < 4; r++) mrow[r] = fmaxf(mrow[r], __shfl_xor(mrow[r], off));
        // ---- online softmax update ----
        float scl[4], psum[4];
#pragma unroll
        for (int r = 0; r < 4; r++) {
            const float mn = fmaxf(m_run[r], mrow[r]);
            scl[r] = __expf(m_run[r] - mn);
            m_run[r] = mn;
            psum[r] = 0.f;
        }
        asm volatile("s_waitcnt lgkmcnt(0)" ::: "memory");  // prev-iter P reads done before overwrite
#pragma unroll
        for (int jn = 0; jn < 4; jn++)
#pragma unroll
            for (int r = 0; r < 4; r++) {
                const float p = __expf(sf[jn][r] - m_run[r]);
                psum[r] += p;
                p_lds[w][kg * 4 + r][jn * 16 + cl] = f2bf(p);
            }
#pragma unroll
        for (int off = 1; off < 16; off <<= 1)
#pragma unroll
            for (int r = 0; r < 4; r++) psum[r] += __shfl_xor(psum[r], off);
#pragma unroll
        for (int r = 0; r < 4; r++) l_run[r] = l_run[r] * scl[r] + psum[r];
#pragma unroll
        for (int d = 0; d < 4; d++)
#pragma unroll
            for (int r = 0; r < 4; r++) accO[d][r] *= scl[r];
        // ---- O += P V  (P via LDS round-trip into A-layout) ----
        asm volatile("s_waitcnt lgkmcnt(0)" ::: "memory");  // P writes visible to whole wave
        const bf16x8 pf0 = ldbf8(&p_lds[w][cl][kg * 8]);
        const bf16x8 pf1 = ldbf8(&p_lds[w][cl][32 + kg * 8]);
#pragma unroll
        for (int d = 0; d < 4; d++) {
            const u16* vp = vt + ((size_t)(b * 64 + d * 16 + cl)) * S + j0 + kg * 8;
            accO[d] = mfma16(pf0, ldbf8(vp), accO[d]);
            accO[d] = mfma16(pf1, ldbf8(vp + 32), accO[d]);
        }
    }
    // ---- write O / l ----
#pragma unroll
    for (int d = 0; d < 4; d++)
#pragma unroll
        for (int r = 0; r < 4; r++) {
            const int i = qbase + kg * 4 + r;
            o[((size_t)(b * S + i)) * 1024 + h * 64 + d * 16 + cl] = f2bf(accO[d][r] / l_run[r]);
        }
}

// ---------------- launcher ----------------
extern "C" void kernel_launch(void* const* d_in, const int* in_sizes, int n_in,
                              void* d_out, int out_size, void* d_ws, size_t ws_size,
                              hipStream_t stream) {
    const float* x     = (const float*)d_in[0];
    const float* gamma = (const float*)d_in[1];
    const float* Wq    = (const float*)d_in[2];
    const float* Wkv   = (const float*)d_in[3];
    const float* Wo    = (const float*)d_in[4];
    float* out = (float*)d_out;
    char* ws = (char*)d_ws;

    // workspace layout (bytes)
    u16* Wq_t  = (u16*)(ws + 0);             // 1024*1024 bf16 = 2 MB
    u16* Wo_t  = (u16*)(ws + (2u << 20));    // 2 MB
    u16* Wkv_t = (u16*)(ws + (4u << 20));    // 128*1024 = 256 KB
    u16* xn    = (u16*)(ws + 4456448u);      // 8 MB
    u16* xb    = (u16*)(ws + 12845056u);     // 8 MB
    u16* qb    = (u16*)(ws + 21233664u);     // 8 MB
    u16* kb    = (u16*)(ws + 29622272u);     // 512 KB
    u16* vtb   = (u16*)(ws + 30146560u);     // 512 KB
    u16* attb  = (u16*)(ws + 30670848u);     // 8 MB  (total ~37.3 MB)

    const dim3 tb(32, 8);
    transpose_cast<<<dim3(32, 32), tb, 0, stream>>>(Wq,  Wq_t,  1024, 1024);
    transpose_cast<<<dim3(32, 4),  tb, 0, stream>>>(Wkv, Wkv_t, 1024, 128);
    transpose_cast<<<dim3(32, 32), tb, 0, stream>>>(Wo,  Wo_t,  1024, 1024);

    ln_cast<<<4096, 256, 0, stream>>>(x, gamma, xn, xb);

    // q = xn @ Wq
    gemm_bt<128, 128, 0><<<dim3(32, 8), 256, 0, stream>>>(xn, Wq_t, qb, nullptr, nullptr, 4096, 1024, 1024);
    // kv = x @ Wkv  (k row-major, v transposed)
    gemm_bt<64, 64, 2><<<dim3(64, 2), 256, 0, stream>>>(xb, Wkv_t, kb, nullptr, vtb, 4096, 128, 1024);
    // flash attention
    attn_fwd<<<1024, 256, 0, stream>>>(qb, kb, vtb, attb);
    // out = att @ Wo
    gemm_bt<128, 128, 1><<<dim3(32, 8), 256, 0, stream>>>(attb, Wo_t, nullptr, out, nullptr, 4096, 1024, 1024);
}

// Round 3
// 143.031 us; speedup vs baseline: 2.0753x; 2.0753x over previous
//
#include <hip/hip_runtime.h>

typedef unsigned short u16;
typedef __attribute__((ext_vector_type(8))) u16    u16x8;
typedef __attribute__((ext_vector_type(4))) u16    u16x4;
typedef __attribute__((ext_vector_type(2))) unsigned u32x2;
typedef __attribute__((ext_vector_type(8))) __bf16 bf16x8;
typedef __attribute__((ext_vector_type(4))) float  f32x4;
typedef __attribute__((ext_vector_type(16))) float f32x16;

__device__ __forceinline__ u16 f2bf(float f) {
    unsigned u = __float_as_uint(f);
    u += 0x7fffu + ((u >> 16) & 1u);   // RNE
    return (u16)(u >> 16);
}
__device__ __forceinline__ bf16x8 ldbf8(const u16* p) {
    return __builtin_bit_cast(bf16x8, *(const u16x8*)p);
}
__device__ __forceinline__ f32x4 mfma16(bf16x8 a, bf16x8 b, f32x4 c) {
    return __builtin_amdgcn_mfma_f32_16x16x32_bf16(a, b, c, 0, 0, 0);
}
__device__ __forceinline__ f32x16 mfma32x(bf16x8 a, bf16x8 b, f32x16 c) {
    return __builtin_amdgcn_mfma_f32_32x32x16_bf16(a, b, c, 0, 0, 0);
}
__device__ __forceinline__ float exp2a(float x) {
    float r; asm("v_exp_f32 %0, %1" : "=v"(r) : "v"(x)); return r;
}
__device__ __forceinline__ unsigned cvtpk(float lo, float hiv) {
    unsigned r; asm("v_cvt_pk_bf16_f32 %0, %1, %2" : "=v"(r) : "v"(lo), "v"(hiv)); return r;
}
// Partner-lane (lane^32) value, robust to v_permlane32_swap operand-order semantics:
// the two outputs jointly hold {own, partner}; xor-with-own isolates the partner.
__device__ __forceinline__ unsigned partner32(unsigned x) {
    u32x2 pr = __builtin_amdgcn_permlane32_swap(x, x, false, false);
    return pr[0] ^ pr[1] ^ x;
}
__device__ __forceinline__ float partner32f(float x) {
    return __uint_as_float(partner32(__float_as_uint(x)));
}
__device__ __forceinline__ bf16x8 pack4(unsigned a, unsigned b, unsigned c, unsigned d) {
    union { unsigned u[4]; bf16x8 v; } t; t.u[0] = a; t.u[1] = b; t.u[2] = c; t.u[3] = d; return t.v;
}

// ---------------- weight transpose + cast:  Wt[n][k] = bf16(W[k][n] * scale) ----------------
__global__ void transpose_cast(const float* __restrict__ W, u16* __restrict__ Wt, int K, int N, float scale) {
    __shared__ float tile[32][33];
    int kb = blockIdx.x * 32, nb = blockIdx.y * 32;
    int tx = threadIdx.x, ty = threadIdx.y;          // (32, 8)
#pragma unroll
    for (int i = 0; i < 32; i += 8)
        tile[ty + i][tx] = W[(size_t)(kb + ty + i) * N + nb + tx];
    __syncthreads();
#pragma unroll
    for (int i = 0; i < 32; i += 8)
        Wt[(size_t)(nb + ty + i) * K + kb + tx] = f2bf(tile[tx][ty + i] * scale);
}

// ---------------- LayerNorm + cast: xn = bf16(LN(x)*gamma), xb = bf16(x) ----------------
__global__ __launch_bounds__(256) void ln_cast(const float* __restrict__ x, const float* __restrict__ gamma,
                                               u16* __restrict__ xn, u16* __restrict__ xb) {
    const int row = blockIdx.x;          // 4096 rows of 1024
    const int t = threadIdx.x;           // 256 threads, 4 floats each
    const float4 v = ((const float4*)(x + (size_t)row * 1024))[t];
    float s  = v.x + v.y + v.z + v.w;
    float s2 = v.x * v.x + v.y * v.y + v.z * v.z + v.w * v.w;
#pragma unroll
    for (int off = 32; off; off >>= 1) { s += __shfl_down(s, off); s2 += __shfl_down(s2, off); }
    __shared__ float red[2][4];
    const int w = t >> 6, lane = t & 63;
    if (lane == 0) { red[0][w] = s; red[1][w] = s2; }
    __syncthreads();
    s  = red[0][0] + red[0][1] + red[0][2] + red[0][3];
    s2 = red[1][0] + red[1][1] + red[1][2] + red[1][3];
    const float mu  = s * (1.0f / 1024.0f);
    const float var = s2 * (1.0f / 1024.0f) - mu * mu;
    const float rs  = rsqrtf(var + 1e-5f);
    const float4 g = ((const float4*)gamma)[t];
    u16x4 on, ob;
    on.x = f2bf((v.x - mu) * rs * g.x); on.y = f2bf((v.y - mu) * rs * g.y);
    on.z = f2bf((v.z - mu) * rs * g.z); on.w = f2bf((v.w - mu) * rs * g.w);
    ob.x = f2bf(v.x); ob.y = f2bf(v.y); ob.z = f2bf(v.z); ob.w = f2bf(v.w);
    ((u16x4*)(xn + (size_t)row * 1024))[t] = on;
    ((u16x4*)(xb + (size_t)row * 1024))[t] = ob;
}

// ---------------- GEMM: C[M,N] = A[M,K] @ Bt[N,K]^T (bf16 in, f32 acc) ----------------
// EPI 0: bf16 row-major C.  EPI 1: f32 row-major C.  EPI 2: KV split (k row-major, v transposed).
template<int BM, int BN, int EPI>
__global__ __launch_bounds__(256) void gemm_bt(const u16* __restrict__ A, const u16* __restrict__ Bt,
                                               u16* __restrict__ Cb, float* __restrict__ Cf,
                                               u16* __restrict__ Cv, int M, int N, int K) {
    constexpr int WM = BM / 2, WN = BN / 2, FM = WM / 16, FN = WN / 16;
    constexpr int CHA = BM * 4, CH = (BM + BN) * 4, ITERS = CH / 256;  // 16B chunks, BK=32
    __shared__ __align__(16) u16 lds[2][(BM + BN) * 32];
    const int tid = threadIdx.x;
    const int m0 = blockIdx.x * BM, n0 = blockIdx.y * BN;
    const int w = tid >> 6, lane = tid & 63, cl = lane & 15, kg = lane >> 4;
    const int wr = w >> 1, wc = w & 1;

    auto stage = [&](int buf, int k0) {
#pragma unroll
        for (int it = 0; it < ITERS; ++it) {
            int c = it * 256 + tid;
            const u16* g;
            if (c < CHA) { int r = c >> 2, cc = c & 3; g = A  + (size_t)(m0 + r) * K + k0 + cc * 8; }
            else { int c2 = c - CHA; int r = c2 >> 2, cc = c2 & 3; g = Bt + (size_t)(n0 + r) * K + k0 + cc * 8; }
            __builtin_amdgcn_global_load_lds(
                (const __attribute__((address_space(1))) unsigned int*)g,
                (__attribute__((address_space(3))) unsigned int*)&lds[buf][c * 8], 16, 0, 0);
        }
    };

    const f32x4 zero = {0.f, 0.f, 0.f, 0.f};
    f32x4 acc[FM][FN];
#pragma unroll
    for (int m = 0; m < FM; m++)
#pragma unroll
        for (int n = 0; n < FN; n++) acc[m][n] = zero;

    const int KT = K / 32;
    stage(0, 0);
    for (int t = 0; t < KT; ++t) {
        __syncthreads();                       // drains vmcnt: buf[t&1] staged, prev reads done
        if (t + 1 < KT) stage((t + 1) & 1, (t + 1) * 32);
        const u16* As = &lds[t & 1][0];
        const u16* Bs = &lds[t & 1][BM * 32];
        bf16x8 af[FM], bfr[FN];
#pragma unroll
        for (int m = 0; m < FM; m++) af[m]  = ldbf8(As + (wr * WM + m * 16 + cl) * 32 + kg * 8);
#pragma unroll
        for (int n = 0; n < FN; n++) bfr[n] = ldbf8(Bs + (wc * WN + n * 16 + cl) * 32 + kg * 8);
#pragma unroll
        for (int m = 0; m < FM; m++)
#pragma unroll
            for (int n = 0; n < FN; n++) acc[m][n] = mfma16(af[m], bfr[n], acc[m][n]);
    }

#pragma unroll
    for (int m = 0; m < FM; m++)
#pragma unroll
        for (int n = 0; n < FN; n++)
#pragma unroll
            for (int r = 0; r < 4; r++) {
                const int row = m0 + wr * WM + m * 16 + kg * 4 + r;   // D: row=(lane>>4)*4+reg
                const int col = n0 + wc * WN + n * 16 + cl;           //    col=lane&15
                const float v = acc[m][n][r];
                if constexpr (EPI == 0) Cb[(size_t)row * N + col] = f2bf(v);
                else if constexpr (EPI == 1) Cf[(size_t)row * N + col] = v;
                else {
                    if (col < 64) Cb[(size_t)row * 64 + col] = f2bf(v);
                    else { int bb = row >> 11, s = row & 2047;
                           Cv[((size_t)bb * 64 + (col - 64)) * 2048 + s] = f2bf(v); }
                }
            }
}

// ---------------- causal flash attention, MQA, Dh=64, swapped-operand 32x32 ----------------
// q: [B,S,1024] bf16 (SCALE*log2e pre-folded into Wq), k: [B,S,64], vt: [B,64,S], o: [B,S,1024]
// Per wave: one 32-q-row tile. S^T = mfma(K,Q) -> lane holds 16 P-vals of q-row (lane&31).
// O^T = mfma(V^T,P) -> col=lane&31=q matches softmax state. Cross-half exchange via partner32.
__global__ __launch_bounds__(256) void attn_fwd(const u16* __restrict__ q, const u16* __restrict__ k,
                                                const u16* __restrict__ vt, u16* __restrict__ o) {
    constexpr int S = 2048;
    const int bid = blockIdx.x;                  // b*256 + h*16 + p
    const int p = bid & 15, h = (bid >> 4) & 15, b = bid >> 8;
    const int tid = threadIdx.x, w = tid >> 6, lane = tid & 63;
    const int l31 = lane & 31;
    const bool hi = (lane & 32) != 0;
    const int hi8 = hi ? 8 : 0;
    // causal load balance: tiles {2p, 2p+1, 62-2p, 63-2p} -> every block does 130 kv-tiles
    const int tw = (w < 2) ? (2 * p + w) : (w == 2 ? 62 - 2 * p : 63 - 2 * p);
    const int q0 = tw * 32;
    const size_t bS = (size_t)b * S;

    __shared__ __align__(16) u16 plds[4 * 32 * 72];   // per-wave O-transpose staging

    bf16x8 qf[4];                                // Q B-frags: col=q=l31, k=hi*8+j (+16*sub)
    {
        const u16* qp = q + (bS + q0 + l31) * 1024 + h * 64 + hi8;
#pragma unroll
        for (int sub = 0; sub < 4; sub++) qf[sub] = ldbf8(qp + sub * 16);
    }

    f32x16 accO0, accO1;                         // O^T d-tiles: col=q=l31, row(r,hi)=d
#pragma unroll
    for (int r = 0; r < 16; r++) { accO0[r] = 0.f; accO1[r] = 0.f; }
    float m_run = -3.0e38f, l_run = 0.f;

    auto loadK = [&](int jt, bf16x8 (&kf)[4]) {
        const u16* kp = k + (bS + jt * 32 + l31) * 64 + hi8;
#pragma unroll
        for (int sub = 0; sub < 4; sub++) kf[sub] = ldbf8(kp + sub * 16);
    };

    auto body = [&](int jt, bf16x8 (&kf)[4], bf16x8 (&kfn)[4]) {
        // S^T[kv][q] = sum_dh K[kv][dh] * Q[q][dh]
        f32x16 s;
#pragma unroll
        for (int r = 0; r < 16; r++) s[r] = 0.f;
#pragma unroll
        for (int sub = 0; sub < 4; sub++) s = mfma32x(kf[sub], qf[sub], s);
        if (jt + 1 <= tw) loadK(jt + 1, kfn);    // prefetch next K under softmax
        bf16x8 vf00, vf01, vf10, vf11;           // V^T A-frags: row=d, k=kv
        {
            const u16* vp = vt + ((size_t)b * 64 + l31) * S + jt * 32 + hi8;
            vf00 = ldbf8(vp);            vf01 = ldbf8(vp + 16);
            vf10 = ldbf8(vp + 32 * S);   vf11 = ldbf8(vp + 32 * S + 16);
        }
        if (jt == tw) {                          // diagonal tile: causal mask
#pragma unroll
            for (int r = 0; r < 16; r++) {
                const int kvl = (r & 3) + 8 * (r >> 2) + (hi ? 4 : 0);
                if (kvl > l31) s[r] = -1e30f;
            }
        }
        float tm = s[0];
#pragma unroll
        for (int r = 1; r < 16; r++) tm = fmaxf(tm, s[r]);
        tm = fmaxf(tm, partner32f(tm));          // combine halves (robust)
        const float mn = fmaxf(m_run, tm);
        const float sc = exp2a(m_run - mn);
        m_run = mn;
        float ps = 0.f;
#pragma unroll
        for (int r = 0; r < 16; r++) { const float pe = exp2a(s[r] - mn); s[r] = pe; ps += pe; }
        ps += partner32f(ps);                    // combine halves (robust)
        l_run = l_run * sc + ps;
#pragma unroll
        for (int r = 0; r < 16; r++) { accO0[r] *= sc; accO1[r] *= sc; }
        // P -> bf16 B-frags (col=q, k=kv). Lane needs kv-octet [hi*8 .. hi*8+7] per 16-kv half:
        //   lo lane: [w0,w1 | partner(w0),partner(w1)]   hi lane: [partner(w2),partner(w3) | w2,w3]
        unsigned w0 = cvtpk(s[0], s[1]),  w1 = cvtpk(s[2], s[3]);
        unsigned w2 = cvtpk(s[4], s[5]),  w3 = cvtpk(s[6], s[7]);
        unsigned pw0 = partner32(w0), pw1 = partner32(w1);
        unsigned pw2 = partner32(w2), pw3 = partner32(w3);
        bf16x8 pf0 = pack4(hi ? pw2 : w0, hi ? pw3 : w1, hi ? w2 : pw0, hi ? w3 : pw1);
        unsigned y0 = cvtpk(s[8], s[9]),   y1 = cvtpk(s[10], s[11]);
        unsigned y2 = cvtpk(s[12], s[13]), y3 = cvtpk(s[14], s[15]);
        unsigned py0 = partner32(y0), py1 = partner32(y1);
        unsigned py2 = partner32(y2), py3 = partner32(y3);
        bf16x8 pf1 = pack4(hi ? py2 : y0, hi ? py3 : y1, hi ? y2 : py0, hi ? y3 : py1);
        accO0 = mfma32x(vf00, pf0, accO0);
        accO0 = mfma32x(vf01, pf1, accO0);
        accO1 = mfma32x(vf10, pf0, accO1);
        accO1 = mfma32x(vf11, pf1, accO1);
    };

    bf16x8 kA[4], kB[4];
    loadK(0, kA);
    for (int jt = 0; jt <= tw; jt += 2) {
        body(jt, kA, kB);
        if (jt + 1 <= tw) body(jt + 1, kB, kA);
    }

    // epilogue: O^T -> LDS [32q][72] -> coalesced global
    const float rl = 1.0f / l_run;
    u16* lb = plds + w * 32 * 72;
#pragma unroll
    for (int i = 0; i < 8; i++) {
        const int d = ((2 * i) & 3) + 8 * ((2 * i) >> 2) + (hi ? 4 : 0);
        *(unsigned*)&lb[l31 * 72 + d]      = cvtpk(accO0[2 * i] * rl, accO0[2 * i + 1] * rl);
        *(unsigned*)&lb[l31 * 72 + 32 + d] = cvtpk(accO1[2 * i] * rl, accO1[2 * i + 1] * rl);
    }
    asm volatile("s_waitcnt lgkmcnt(0)" ::: "memory");
#pragma unroll
    for (int i = 0; i < 4; i++) {
        const int qq = i * 8 + (lane >> 3), dd = (lane & 7) * 8;
        *(u16x8*)(o + (bS + q0 + qq) * 1024 + h * 64 + dd) = *(const u16x8*)&lb[qq * 72 + dd];
    }
}

// ---------------- launcher ----------------
extern "C" void kernel_launch(void* const* d_in, const int* in_sizes, int n_in,
                              void* d_out, int out_size, void* d_ws, size_t ws_size,
                              hipStream_t stream) {
    const float* x     = (const float*)d_in[0];
    const float* gamma = (const float*)d_in[1];
    const float* Wq    = (const float*)d_in[2];
    const float* Wkv   = (const float*)d_in[3];
    const float* Wo    = (const float*)d_in[4];
    float* out = (float*)d_out;
    char* ws = (char*)d_ws;

    u16* Wq_t  = (u16*)(ws + 0);             // 2 MB
    u16* Wo_t  = (u16*)(ws + (2u << 20));    // 2 MB
    u16* Wkv_t = (u16*)(ws + (4u << 20));    // 256 KB
    u16* xn    = (u16*)(ws + 4456448u);      // 8 MB
    u16* xb    = (u16*)(ws + 12845056u);     // 8 MB
    u16* qb    = (u16*)(ws + 21233664u);     // 8 MB
    u16* kb    = (u16*)(ws + 29622272u);     // 512 KB
    u16* vtb   = (u16*)(ws + 30146560u);     // 512 KB
    u16* attb  = (u16*)(ws + 30670848u);     // 8 MB

    const dim3 tb(32, 8);
    const float qscale = 0.125f * 1.44269504f;   // SCALE * log2(e) folded into Wq
    transpose_cast<<<dim3(32, 32), tb, 0, stream>>>(Wq,  Wq_t,  1024, 1024, qscale);
    transpose_cast<<<dim3(32, 4),  tb, 0, stream>>>(Wkv, Wkv_t, 1024, 128, 1.0f);
    transpose_cast<<<dim3(32, 32), tb, 0, stream>>>(Wo,  Wo_t,  1024, 1024, 1.0f);

    ln_cast<<<4096, 256, 0, stream>>>(x, gamma, xn, xb);

    gemm_bt<128, 128, 0><<<dim3(32, 8), 256, 0, stream>>>(xn, Wq_t, qb, nullptr, nullptr, 4096, 1024, 1024);
    gemm_bt<64, 64, 2><<<dim3(64, 2), 256, 0, stream>>>(xb, Wkv_t, kb, nullptr, vtb, 4096, 128, 1024);
    attn_fwd<<<512, 256, 0, stream>>>(qb, kb, vtb, attb);
    gemm_bt<128, 128, 1><<<dim3(32, 8), 256, 0, stream>>>(attb, Wo_t, nullptr, out, nullptr, 4096, 1024, 1024);
}

// Round 4
// 142.725 us; speedup vs baseline: 2.0797x; 1.0021x over previous
//
#include <hip/hip_runtime.h>

typedef unsigned short u16;
typedef __attribute__((ext_vector_type(8))) u16    u16x8;
typedef __attribute__((ext_vector_type(4))) u16    u16x4;
typedef __attribute__((ext_vector_type(2))) unsigned u32x2;
typedef __attribute__((ext_vector_type(4))) unsigned u32x4;
typedef __attribute__((ext_vector_type(8))) __bf16 bf16x8;
typedef __attribute__((ext_vector_type(4))) float  f32x4;
typedef __attribute__((ext_vector_type(16))) float f32x16;

__device__ __forceinline__ u16 f2bf(float f) {
    unsigned u = __float_as_uint(f);
    u += 0x7fffu + ((u >> 16) & 1u);   // RNE
    return (u16)(u >> 16);
}
__device__ __forceinline__ bf16x8 ldbf8(const u16* p) {
    return __builtin_bit_cast(bf16x8, *(const u16x8*)p);
}
__device__ __forceinline__ f32x4 mfma16(bf16x8 a, bf16x8 b, f32x4 c) {
    return __builtin_amdgcn_mfma_f32_16x16x32_bf16(a, b, c, 0, 0, 0);
}
__device__ __forceinline__ f32x16 mfma32x(bf16x8 a, bf16x8 b, f32x16 c) {
    return __builtin_amdgcn_mfma_f32_32x32x16_bf16(a, b, c, 0, 0, 0);
}
__device__ __forceinline__ float exp2a(float x) {
    float r; asm("v_exp_f32 %0, %1" : "=v"(r) : "v"(x)); return r;
}
__device__ __forceinline__ unsigned cvtpk(float lo, float hiv) {
    unsigned r; asm("v_cvt_pk_bf16_f32 %0, %1, %2" : "=v"(r) : "v"(lo), "v"(hiv)); return r;
}
// v_permlane32_swap_b32 via builtin (returns both outputs; safe w/ same-reg inputs):
// r[0] = {a.lo | b.lo-of-partner}, r[1] = {a.hi-of-partner | b.hi}
__device__ __forceinline__ u32x2 permswap2(unsigned a, unsigned b) {
    return __builtin_amdgcn_permlane32_swap(a, b, false, false);
}
__device__ __forceinline__ float combine_max(float x) {   // orientation-robust
    u32x2 pr = permswap2(__float_as_uint(x), __float_as_uint(x));
    return fmaxf(__uint_as_float(pr[0]), __uint_as_float(pr[1]));
}
__device__ __forceinline__ float combine_sum(float x) {   // orientation-robust
    u32x2 pr = permswap2(__float_as_uint(x), __float_as_uint(x));
    return __uint_as_float(pr[0]) + __uint_as_float(pr[1]);
}
__device__ __forceinline__ bf16x8 pack4(unsigned a, unsigned b, unsigned c, unsigned d) {
    union { unsigned u[4]; bf16x8 v; } t; t.u[0] = a; t.u[1] = b; t.u[2] = c; t.u[3] = d; return t.v;
}

// ---------------- weight transpose + cast:  Wt[n][k] = bf16(W[k][n] * scale) ----------------
__global__ void transpose_cast(const float* __restrict__ W, u16* __restrict__ Wt, int K, int N, float scale) {
    __shared__ float tile[32][33];
    int kb = blockIdx.x * 32, nb = blockIdx.y * 32;
    int tx = threadIdx.x, ty = threadIdx.y;          // (32, 8)
#pragma unroll
    for (int i = 0; i < 32; i += 8)
        tile[ty + i][tx] = W[(size_t)(kb + ty + i) * N + nb + tx];
    __syncthreads();
#pragma unroll
    for (int i = 0; i < 32; i += 8)
        Wt[(size_t)(nb + ty + i) * K + kb + tx] = f2bf(tile[tx][ty + i] * scale);
}

// ---------------- LayerNorm + cast: xn = bf16(LN(x)*gamma), xb = bf16(x) ----------------
__global__ __launch_bounds__(256) void ln_cast(const float* __restrict__ x, const float* __restrict__ gamma,
                                               u16* __restrict__ xn, u16* __restrict__ xb) {
    const int row = blockIdx.x;          // 4096 rows of 1024
    const int t = threadIdx.x;           // 256 threads, 4 floats each
    const float4 v = ((const float4*)(x + (size_t)row * 1024))[t];
    float s  = v.x + v.y + v.z + v.w;
    float s2 = v.x * v.x + v.y * v.y + v.z * v.z + v.w * v.w;
#pragma unroll
    for (int off = 32; off; off >>= 1) { s += __shfl_down(s, off); s2 += __shfl_down(s2, off); }
    __shared__ float red[2][4];
    const int w = t >> 6, lane = t & 63;
    if (lane == 0) { red[0][w] = s; red[1][w] = s2; }
    __syncthreads();
    s  = red[0][0] + red[0][1] + red[0][2] + red[0][3];
    s2 = red[1][0] + red[1][1] + red[1][2] + red[1][3];
    const float mu  = s * (1.0f / 1024.0f);
    const float var = s2 * (1.0f / 1024.0f) - mu * mu;
    const float rs  = rsqrtf(var + 1e-5f);
    const float4 g = ((const float4*)gamma)[t];
    u16x4 on, ob;
    on.x = f2bf((v.x - mu) * rs * g.x); on.y = f2bf((v.y - mu) * rs * g.y);
    on.z = f2bf((v.z - mu) * rs * g.z); on.w = f2bf((v.w - mu) * rs * g.w);
    ob.x = f2bf(v.x); ob.y = f2bf(v.y); ob.z = f2bf(v.z); ob.w = f2bf(v.w);
    ((u16x4*)(xn + (size_t)row * 1024))[t] = on;
    ((u16x4*)(xb + (size_t)row * 1024))[t] = ob;
}

// ---------------- GEMM: C[M,N] = A[M,K] @ Bt[N,K]^T (bf16 in, f32 acc) ----------------
template<int BM, int BN, int EPI>
__global__ __launch_bounds__(256) void gemm_bt(const u16* __restrict__ A, const u16* __restrict__ Bt,
                                               u16* __restrict__ Cb, float* __restrict__ Cf,
                                               u16* __restrict__ Cv, int M, int N, int K) {
    constexpr int WM = BM / 2, WN = BN / 2, FM = WM / 16, FN = WN / 16;
    constexpr int CHA = BM * 4, CH = (BM + BN) * 4, ITERS = CH / 256;  // 16B chunks, BK=32
    __shared__ __align__(16) u16 lds[2][(BM + BN) * 32];
    const int tid = threadIdx.x;
    const int m0 = blockIdx.x * BM, n0 = blockIdx.y * BN;
    const int w = tid >> 6, lane = tid & 63, cl = lane & 15, kg = lane >> 4;
    const int wr = w >> 1, wc = w & 1;

    auto stage = [&](int buf, int k0) {
#pragma unroll
        for (int it = 0; it < ITERS; ++it) {
            int c = it * 256 + tid;
            const u16* g;
            if (c < CHA) { int r = c >> 2, cc = c & 3; g = A  + (size_t)(m0 + r) * K + k0 + cc * 8; }
            else { int c2 = c - CHA; int r = c2 >> 2, cc = c2 & 3; g = Bt + (size_t)(n0 + r) * K + k0 + cc * 8; }
            __builtin_amdgcn_global_load_lds(
                (const __attribute__((address_space(1))) unsigned int*)g,
                (__attribute__((address_space(3))) unsigned int*)&lds[buf][c * 8], 16, 0, 0);
        }
    };

    const f32x4 zero = {0.f, 0.f, 0.f, 0.f};
    f32x4 acc[FM][FN];
#pragma unroll
    for (int m = 0; m < FM; m++)
#pragma unroll
        for (int n = 0; n < FN; n++) acc[m][n] = zero;

    const int KT = K / 32;
    stage(0, 0);
    for (int t = 0; t < KT; ++t) {
        __syncthreads();
        if (t + 1 < KT) stage((t + 1) & 1, (t + 1) * 32);
        const u16* As = &lds[t & 1][0];
        const u16* Bs = &lds[t & 1][BM * 32];
        bf16x8 af[FM], bfr[FN];
#pragma unroll
        for (int m = 0; m < FM; m++) af[m]  = ldbf8(As + (wr * WM + m * 16 + cl) * 32 + kg * 8);
#pragma unroll
        for (int n = 0; n < FN; n++) bfr[n] = ldbf8(Bs + (wc * WN + n * 16 + cl) * 32 + kg * 8);
#pragma unroll
        for (int m = 0; m < FM; m++)
#pragma unroll
            for (int n = 0; n < FN; n++) acc[m][n] = mfma16(af[m], bfr[n], acc[m][n]);
    }

#pragma unroll
    for (int m = 0; m < FM; m++)
#pragma unroll
        for (int n = 0; n < FN; n++)
#pragma unroll
            for (int r = 0; r < 4; r++) {
                const int row = m0 + wr * WM + m * 16 + kg * 4 + r;
                const int col = n0 + wc * WN + n * 16 + cl;
                const float v = acc[m][n][r];
                if constexpr (EPI == 0) Cb[(size_t)row * N + col] = f2bf(v);
                else if constexpr (EPI == 1) Cf[(size_t)row * N + col] = v;
                else {
                    if (col < 64) Cb[(size_t)row * 64 + col] = f2bf(v);
                    else { int bb = row >> 11, s = row & 2047;
                           Cv[((size_t)bb * 64 + (col - 64)) * 2048 + s] = f2bf(v); }
                }
            }
}

// ---------------- causal flash attention, MQA, Dh=64, swapped-operand 32x32 ----------------
// Block = one (b,h,q-tile). 4 waves split kv-tiles jt ≡ w (mod 4); LDS pairwise merge at end.
// q: [B,S,1024] bf16 (SCALE*log2e folded into Wq), k: [B,S,64], vt: [B,64,S], o: [B,S,1024]
__global__ __launch_bounds__(256) void attn_fwd(const u16* __restrict__ q, const u16* __restrict__ k,
                                                const u16* __restrict__ vt, u16* __restrict__ o) {
    constexpr int S = 2048;
    const int bid = blockIdx.x;                  // tt*32 + bh : same-t blocks adjacent -> big-t first
    const int bh = bid & 31, t = 63 - (bid >> 5);
    const int h = bh & 15, b = bh >> 4;
    const int tid = threadIdx.x, w = tid >> 6, lane = tid & 63;
    const int l31 = lane & 31;
    const bool hi = (lane & 32) != 0;
    const int hi8 = hi ? 8 : 0;
    const int q0 = t * 32;
    const size_t bS = (size_t)b * S;

    // merge buffers: per lane 80B = 16 u32 acc(bf16 pairs) + m + l + pad
    __shared__ __align__(16) unsigned mbuf[2][64][20];

    bf16x8 qf[4];                                // Q B-frags: col=q=l31, k=hi*8+j (+16*sub)
    {
        const u16* qp = q + (bS + q0 + l31) * 1024 + h * 64 + hi8;
#pragma unroll
        for (int sub = 0; sub < 4; sub++) qf[sub] = ldbf8(qp + sub * 16);
    }

    f32x16 accO0, accO1;                         // O^T d-tiles: col=q=l31, row(r,hi)=d
#pragma unroll
    for (int r = 0; r < 16; r++) { accO0[r] = 0.f; accO1[r] = 0.f; }
    float m_run = -3.0e38f, l_run = 0.f;

    auto loadK = [&](int jt, bf16x8 (&kf)[4]) {
        const u16* kp = k + (bS + jt * 32 + l31) * 64 + hi8;
#pragma unroll
        for (int sub = 0; sub < 4; sub++) kf[sub] = ldbf8(kp + sub * 16);
    };

    auto body = [&](int jt, bf16x8 (&kf)[4], bf16x8 (&kfn)[4]) {
        f32x16 s;
#pragma unroll
        for (int r = 0; r < 16; r++) s[r] = 0.f;
#pragma unroll
        for (int sub = 0; sub < 4; sub++) s = mfma32x(kf[sub], qf[sub], s);
        if (jt + 4 <= t) loadK(jt + 4, kfn);     // prefetch this wave's next K
        bf16x8 vf00, vf01, vf10, vf11;           // V^T A-frags: row=d, k=kv
        {
            const u16* vp = vt + ((size_t)b * 64 + l31) * S + jt * 32 + hi8;
            vf00 = ldbf8(vp);            vf01 = ldbf8(vp + 16);
            vf10 = ldbf8(vp + 32 * S);   vf11 = ldbf8(vp + 32 * S + 16);
        }
        if (jt == t) {                           // diagonal tile: causal mask
#pragma unroll
            for (int r = 0; r < 16; r++) {
                const int kvl = (r & 3) + 8 * (r >> 2) + (hi ? 4 : 0);
                if (kvl > l31) s[r] = -1e30f;
            }
        }
        // row max (max3-shaped tree) + robust cross-half combine
        float tm = fmaxf(fmaxf(s[0], s[1]), s[2]);
#pragma unroll
        for (int r = 3; r < 15; r += 2) tm = fmaxf(fmaxf(tm, s[r]), s[r + 1]);
        tm = fmaxf(tm, s[15]);
        tm = combine_max(tm);
        // defer-max: only rescale when max grows by >5 (log2 domain; P bounded by 32)
        if (!__all(tm <= m_run + 5.0f)) {
            const float mn = fmaxf(m_run, tm);
            const float sc = exp2a(m_run - mn);
            m_run = mn;
            l_run *= sc;
#pragma unroll
            for (int r = 0; r < 16; r++) { accO0[r] *= sc; accO1[r] *= sc; }
        }
        float ps = 0.f;
#pragma unroll
        for (int r = 0; r < 16; r++) { const float pe = exp2a(s[r] - m_run); s[r] = pe; ps += pe; }
        l_run += combine_sum(ps);
        // P -> bf16 B-frags via 2 permlane per 16-kv half (T12 cheap form)
        unsigned w0 = cvtpk(s[0], s[1]),  w1 = cvtpk(s[2], s[3]);
        unsigned w2 = cvtpk(s[4], s[5]),  w3 = cvtpk(s[6], s[7]);
        u32x2 r02 = permswap2(w0, w2), r13 = permswap2(w1, w3);
        bf16x8 pf0 = pack4(r02[0], r13[0], r02[1], r13[1]);
        unsigned y0 = cvtpk(s[8], s[9]),   y1 = cvtpk(s[10], s[11]);
        unsigned y2 = cvtpk(s[12], s[13]), y3 = cvtpk(s[14], s[15]);
        u32x2 t02 = permswap2(y0, y2), t13 = permswap2(y1, y3);
        bf16x8 pf1 = pack4(t02[0], t13[0], t02[1], t13[1]);
        accO0 = mfma32x(vf00, pf0, accO0);
        accO0 = mfma32x(vf01, pf1, accO0);
        accO1 = mfma32x(vf10, pf0, accO1);
        accO1 = mfma32x(vf11, pf1, accO1);
    };

    bf16x8 kA[4], kB[4];
    if (w <= t) loadK(w, kA);
    for (int jt = w; jt <= t; jt += 8) {
        body(jt, kA, kB);
        if (jt + 4 <= t) body(jt + 4, kB, kA);
    }

    // ---- LDS pairwise merge: (w1,w3) dump; (w0,w2) absorb; w2 dump; w0 absorb ----
    auto dump = [&](int bi) {
        unsigned* p = &mbuf[bi][lane][0];
        u32x4 g0, g1, g2, g3;
#pragma unroll
        for (int i = 0; i < 4; i++) {
            g0[i] = cvtpk(accO0[2 * i], accO0[2 * i + 1]);
            g1[i] = cvtpk(accO0[8 + 2 * i], accO0[9 + 2 * i]);
            g2[i] = cvtpk(accO1[2 * i], accO1[2 * i + 1]);
            g3[i] = cvtpk(accO1[8 + 2 * i], accO1[9 + 2 * i]);
        }
        ((u32x4*)p)[0] = g0; ((u32x4*)p)[1] = g1;
        ((u32x4*)p)[2] = g2; ((u32x4*)p)[3] = g3;
        p[16] = __float_as_uint(m_run); p[17] = __float_as_uint(l_run);
    };
    auto absorb = [&](int bi) {
        const unsigned* p = &mbuf[bi][lane][0];
        u32x4 g0 = ((const u32x4*)p)[0], g1 = ((const u32x4*)p)[1];
        u32x4 g2 = ((const u32x4*)p)[2], g3 = ((const u32x4*)p)[3];
        const float mb = __uint_as_float(p[16]), lb = __uint_as_float(p[17]);
        const float mn = fmaxf(m_run, mb);
        const float sa = exp2a(m_run - mn), sb = exp2a(mb - mn);
        m_run = mn;
        l_run = sa * l_run + sb * lb;
#pragma unroll
        for (int i = 0; i < 4; i++) {
            accO0[2 * i]     = sa * accO0[2 * i]     + sb * __uint_as_float(g0[i] << 16);
            accO0[2 * i + 1] = sa * accO0[2 * i + 1] + sb * __uint_as_float(g0[i] & 0xffff0000u);
            accO0[8 + 2 * i] = sa * accO0[8 + 2 * i] + sb * __uint_as_float(g1[i] << 16);
            accO0[9 + 2 * i] = sa * accO0[9 + 2 * i] + sb * __uint_as_float(g1[i] & 0xffff0000u);
            accO1[2 * i]     = sa * accO1[2 * i]     + sb * __uint_as_float(g2[i] << 16);
            accO1[2 * i + 1] = sa * accO1[2 * i + 1] + sb * __uint_as_float(g2[i] & 0xffff0000u);
            accO1[8 + 2 * i] = sa * accO1[8 + 2 * i] + sb * __uint_as_float(g3[i] << 16);
            accO1[9 + 2 * i] = sa * accO1[9 + 2 * i] + sb * __uint_as_float(g3[i] & 0xffff0000u);
        }
    };

    if (w == 1) dump(0);
    if (w == 3) dump(1);
    __syncthreads();
    if (w == 0) absorb(0);
    if (w == 2) absorb(1);
    __syncthreads();
    if (w == 2) dump(0);
    __syncthreads();

    if (w == 0) {
        absorb(0);
        // epilogue: O^T -> LDS [32q][72] (aliases mbuf[1]) -> coalesced global
        const float rl = 1.0f / l_run;
        u16* lb = (u16*)&mbuf[1][0][0];
#pragma unroll
        for (int i = 0; i < 8; i++) {
            const int d = ((2 * i) & 3) + 8 * ((2 * i) >> 2) + (hi ? 4 : 0);
            *(unsigned*)&lb[l31 * 72 + d]      = cvtpk(accO0[2 * i] * rl, accO0[2 * i + 1] * rl);
            *(unsigned*)&lb[l31 * 72 + 32 + d] = cvtpk(accO1[2 * i] * rl, accO1[2 * i + 1] * rl);
        }
        asm volatile("s_waitcnt lgkmcnt(0)" ::: "memory");
#pragma unroll
        for (int i = 0; i < 4; i++) {
            const int qq = i * 8 + (lane >> 3), dd = (lane & 7) * 8;
            *(u16x8*)(o + (bS + q0 + qq) * 1024 + h * 64 + dd) = *(const u16x8*)&lb[qq * 72 + dd];
        }
    }
}

// ---------------- launcher ----------------
extern "C" void kernel_launch(void* const* d_in, const int* in_sizes, int n_in,
                              void* d_out, int out_size, void* d_ws, size_t ws_size,
                              hipStream_t stream) {
    const float* x     = (const float*)d_in[0];
    const float* gamma = (const float*)d_in[1];
    const float* Wq    = (const float*)d_in[2];
    const float* Wkv   = (const float*)d_in[3];
    const float* Wo    = (const float*)d_in[4];
    float* out = (float*)d_out;
    char* ws = (char*)d_ws;

    u16* Wq_t  = (u16*)(ws + 0);             // 2 MB
    u16* Wo_t  = (u16*)(ws + (2u << 20));    // 2 MB
    u16* Wkv_t = (u16*)(ws + (4u << 20));    // 256 KB
    u16* xn    = (u16*)(ws + 4456448u);      // 8 MB
    u16* xb    = (u16*)(ws + 12845056u);     // 8 MB
    u16* qb    = (u16*)(ws + 21233664u);     // 8 MB
    u16* kb    = (u16*)(ws + 29622272u);     // 512 KB
    u16* vtb   = (u16*)(ws + 30146560u);     // 512 KB
    u16* attb  = (u16*)(ws + 30670848u);     // 8 MB

    const dim3 tb(32, 8);
    const float qscale = 0.125f * 1.44269504f;   // SCALE * log2(e) folded into Wq
    transpose_cast<<<dim3(32, 32), tb, 0, stream>>>(Wq,  Wq_t,  1024, 1024, qscale);
    transpose_cast<<<dim3(32, 4),  tb, 0, stream>>>(Wkv, Wkv_t, 1024, 128, 1.0f);
    transpose_cast<<<dim3(32, 32), tb, 0, stream>>>(Wo,  Wo_t,  1024, 1024, 1.0f);

    ln_cast<<<4096, 256, 0, stream>>>(x, gamma, xn, xb);

    gemm_bt<128, 128, 0><<<dim3(32, 8), 256, 0, stream>>>(xn, Wq_t, qb, nullptr, nullptr, 4096, 1024, 1024);
    gemm_bt<64, 64, 2><<<dim3(64, 2), 256, 0, stream>>>(xb, Wkv_t, kb, nullptr, vtb, 4096, 128, 1024);
    attn_fwd<<<2048, 256, 0, stream>>>(qb, kb, vtb, attb);
    gemm_bt<128, 128, 1><<<dim3(32, 8), 256, 0, stream>>>(attb, Wo_t, nullptr, out, nullptr, 4096, 1024, 1024);
}